// Round 1
// baseline (825.373 us; speedup 1.0000x reference)
//
#include <hip/hip_runtime.h>
#include <math.h>

#define HDIM 7168
#define NEXP 256
#define NTOK 8192

// ---------------------------------------------------------------------------
// Kernel 1: router GEMM  logits[t][e] = sum_k hs[t][k] * W[e][k]
// BM=64, BN=64, BK=32, 256 threads, 4x4 micro-tile per thread.
// fp32 FMA inner chains (len 32) + fp64 cross-tile accumulator for accuracy
// (index outputs require exact top-k match; logit error here ~2e-7).
// ---------------------------------------------------------------------------
__global__ __launch_bounds__(256, 2)
void router_gemm_kernel(const float* __restrict__ hs,
                        const float* __restrict__ W,
                        float* __restrict__ logits)
{
    __shared__ float As[32][64];   // [k][m]
    __shared__ float Bs[32][64];   // [k][n]

    const int tid = threadIdx.x;
    const int bm = blockIdx.y * 64;
    const int bn = blockIdx.x * 64;
    const int tx = tid & 15;        // n micro index
    const int ty = tid >> 4;        // m micro index
    const int lr = tid >> 2;        // staging row 0..63
    const int lc = (tid & 3) << 2;  // staging k 0,4,8,12 (+16 for 2nd half)

    const float* Arow = hs + (size_t)(bm + lr) * HDIM + lc;
    const float* Brow = W  + (size_t)(bn + lr) * HDIM + lc;

    double acc[4][4];
#pragma unroll
    for (int i = 0; i < 4; i++)
#pragma unroll
        for (int j = 0; j < 4; j++) acc[i][j] = 0.0;

    for (int k0 = 0; k0 < HDIM; k0 += 32) {
        float4 a0 = *(const float4*)(Arow + k0);
        float4 a1 = *(const float4*)(Arow + k0 + 16);
        float4 b0 = *(const float4*)(Brow + k0);
        float4 b1 = *(const float4*)(Brow + k0 + 16);
        __syncthreads();   // previous iteration's LDS reads done
        As[lc + 0][lr] = a0.x; As[lc + 1][lr] = a0.y;
        As[lc + 2][lr] = a0.z; As[lc + 3][lr] = a0.w;
        As[lc + 16][lr] = a1.x; As[lc + 17][lr] = a1.y;
        As[lc + 18][lr] = a1.z; As[lc + 19][lr] = a1.w;
        Bs[lc + 0][lr] = b0.x; Bs[lc + 1][lr] = b0.y;
        Bs[lc + 2][lr] = b0.z; Bs[lc + 3][lr] = b0.w;
        Bs[lc + 16][lr] = b1.x; Bs[lc + 17][lr] = b1.y;
        Bs[lc + 18][lr] = b1.z; Bs[lc + 19][lr] = b1.w;
        __syncthreads();

        float inner[4][4];
#pragma unroll
        for (int i = 0; i < 4; i++)
#pragma unroll
            for (int j = 0; j < 4; j++) inner[i][j] = 0.0f;

#pragma unroll
        for (int k = 0; k < 32; k++) {
            float4 av = *(const float4*)(&As[k][ty << 2]);
            float4 bv = *(const float4*)(&Bs[k][tx << 2]);
            float aa[4] = {av.x, av.y, av.z, av.w};
            float bb[4] = {bv.x, bv.y, bv.z, bv.w};
#pragma unroll
            for (int i = 0; i < 4; i++)
#pragma unroll
                for (int j = 0; j < 4; j++)
                    inner[i][j] = fmaf(aa[i], bb[j], inner[i][j]);
        }
#pragma unroll
        for (int i = 0; i < 4; i++)
#pragma unroll
            for (int j = 0; j < 4; j++) acc[i][j] += (double)inner[i][j];
    }

#pragma unroll
    for (int i = 0; i < 4; i++) {
        const int m = bm + (ty << 2) + i;
#pragma unroll
        for (int j = 0; j < 4; j++) {
            const int n = bn + (tx << 2) + j;
            logits[(size_t)m * NEXP + n] = (float)acc[i][j];
        }
    }
}

// ---------------------------------------------------------------------------
// Kernel 2: one wave per token. lane l holds experts 4l..4l+3.
// Replicates jax.lax.top_k semantics exactly: descending, ties -> lower index;
// unselected groups contribute literal 0.0f candidates.
// ---------------------------------------------------------------------------
__global__ __launch_bounds__(256)
void router_topk_kernel(const float* __restrict__ logits,
                        const float* __restrict__ bias,
                        const float* __restrict__ corr,
                        float* __restrict__ out)
{
    const int lane = threadIdx.x & 63;
    const int wave = threadIdx.x >> 6;
    const int t = blockIdx.x * 4 + wave;
    const float* row = logits + (size_t)t * NEXP;
    const int e0 = lane << 2;

    float4 lg = *(const float4*)(row + e0);
    float4 bb = *(const float4*)(bias + e0);
    float4 cc = *(const float4*)(corr + e0);

    float xs[4] = {lg.x + bb.x, lg.y + bb.y, lg.z + bb.z, lg.w + bb.w};
    float cs[4] = {cc.x, cc.y, cc.z, cc.w};
    float s[4], sc[4], mv[4];
#pragma unroll
    for (int i = 0; i < 4; i++) {
        s[i] = 1.0f / (1.0f + expf(-xs[i]));
        sc[i] = s[i] + cs[i];
    }

    // ---- per-group (32 experts = 8 lanes) top-2 sum ----
    float m1 = fmaxf(sc[0], sc[1]);
    float m2 = fminf(sc[0], sc[1]);
    if (sc[2] > m1) { m2 = m1; m1 = sc[2]; } else { m2 = fmaxf(m2, sc[2]); }
    if (sc[3] > m1) { m2 = m1; m1 = sc[3]; } else { m2 = fmaxf(m2, sc[3]); }
#pragma unroll
    for (int off = 1; off <= 4; off <<= 1) {
        float o1 = __shfl_xor(m1, off);
        float o2 = __shfl_xor(m2, off);
        float hi = fmaxf(m1, o1);
        float lo = fminf(m1, o1);
        m1 = hi;
        m2 = fmaxf(lo, fmaxf(m2, o2));
    }
    const float gscore = m1 + m2;

    // ---- broadcast all 8 group scores, compute top-4 group mask ----
    float gs[8];
#pragma unroll
    for (int j = 0; j < 8; j++) gs[j] = __shfl(gscore, j << 3);
    const int g = lane >> 3;
    int rank = 0;
#pragma unroll
    for (int j = 0; j < 8; j++)
        rank += ((gs[j] > gs[g]) || ((gs[j] == gs[g]) && (j < g))) ? 1 : 0;
    const bool sel = (rank < 4);

#pragma unroll
    for (int i = 0; i < 4; i++) mv[i] = sel ? sc[i] : 0.0f;

    // ---- iterative top-8 wave argmax (stable: ties -> lower index) ----
    int oidx[8];
    float ow[8];
    float wsum = 0.0f;
#pragma unroll
    for (int r = 0; r < 8; r++) {
        float bv = mv[0]; int bi = e0;
        if (mv[1] > bv) { bv = mv[1]; bi = e0 + 1; }
        if (mv[2] > bv) { bv = mv[2]; bi = e0 + 2; }
        if (mv[3] > bv) { bv = mv[3]; bi = e0 + 3; }
#pragma unroll
        for (int off = 32; off >= 1; off >>= 1) {
            float ov = __shfl_xor(bv, off);
            int oi = __shfl_xor(bi, off);
            if ((ov > bv) || ((ov == bv) && (oi < bi))) { bv = ov; bi = oi; }
        }
        // all lanes now agree on (bv, bi)
        const int wl = bi >> 2;
        const int slot = bi & 3;
        float sraw = (slot == 0) ? s[0] : (slot == 1) ? s[1] : (slot == 2) ? s[2] : s[3];
        sraw = __shfl(sraw, wl);
        if (lane == wl) {
            if (slot == 0) mv[0] = -1e30f;
            else if (slot == 1) mv[1] = -1e30f;
            else if (slot == 2) mv[2] = -1e30f;
            else mv[3] = -1e30f;
        }
        oidx[r] = bi;
        ow[r] = sraw;
        wsum += sraw;
    }

    if (lane == 0) {
        const float d = wsum + 1e-20f;
        float* oi_p = out + (size_t)t * 8;
        float* ow_p = out + (size_t)NTOK * 8 + (size_t)t * 8;
#pragma unroll
        for (int r = 0; r < 8; r++) {
            oi_p[r] = (float)oidx[r];
            ow_p[r] = (ow[r] / d) * 2.5f;
        }
    }
}

extern "C" void kernel_launch(void* const* d_in, const int* in_sizes, int n_in,
                              void* d_out, int out_size, void* d_ws, size_t ws_size,
                              hipStream_t stream)
{
    const float* hs   = (const float*)d_in[0];   // [8192, 7168]
    const float* W    = (const float*)d_in[1];   // [256, 7168]
    const float* b    = (const float*)d_in[2];   // [256]
    const float* corr = (const float*)d_in[3];   // [256]
    float* out = (float*)d_out;                  // 65536 idx-as-float + 65536 weights
    float* logits = (float*)d_ws;                // 8192*256 fp32 = 8 MB scratch

    dim3 g1(NEXP / 64, NTOK / 64);               // (4, 128) -> 512 blocks
    router_gemm_kernel<<<g1, 256, 0, stream>>>(hs, W, logits);
    router_topk_kernel<<<NTOK / 4, 256, 0, stream>>>(logits, b, corr, out);
}

// Round 2
// 728.232 us; speedup vs baseline: 1.1334x; 1.1334x over previous
//
#include <hip/hip_runtime.h>
#include <math.h>

#define HDIM 7168
#define NEXP 256
#define NTOK 8192
#define KSPLIT 4
#define KCHUNK (HDIM / KSPLIT)   // 1792

// ---------------------------------------------------------------------------
// Kernel 1: router GEMM  logits[t][e] = sum_k hs[t][k] * W[e][k]
// BM=64, BN=64, BK=32, 256 threads, 4x4 micro-tile, split-K=4 via blockIdx.z.
// LDS leading dim padded to 68 -> staging writes are 2-way (free) instead of
// 4-way bank-conflicted. fp32 inner chains (len 32) + fp64 per-chunk
// accumulator; chunks combined with hw fp32 atomics (order error ~1e-7,
// well under observed top-k decision gaps).
// ---------------------------------------------------------------------------
__global__ __launch_bounds__(256, 4)
void router_gemm_kernel(const float* __restrict__ hs,
                        const float* __restrict__ W,
                        float* __restrict__ logits)
{
    __shared__ float As[32][68];   // [k][m], pad 68: 68%32=4 spreads write banks
    __shared__ float Bs[32][68];   // [k][n]

    const int tid = threadIdx.x;
    const int bm = blockIdx.y * 64;
    const int bn = blockIdx.x * 64;
    const int kbase = blockIdx.z * KCHUNK;
    const int tx = tid & 15;        // n micro index
    const int ty = tid >> 4;        // m micro index
    const int lr = tid >> 2;        // staging row 0..63
    const int lc = (tid & 3) << 2;  // staging k 0,4,8,12 (+16 for 2nd half)

    const float* Arow = hs + (size_t)(bm + lr) * HDIM + lc;
    const float* Brow = W  + (size_t)(bn + lr) * HDIM + lc;

    double acc[4][4];
#pragma unroll
    for (int i = 0; i < 4; i++)
#pragma unroll
        for (int j = 0; j < 4; j++) acc[i][j] = 0.0;

    for (int k0 = kbase; k0 < kbase + KCHUNK; k0 += 32) {
        float4 a0 = *(const float4*)(Arow + k0);
        float4 a1 = *(const float4*)(Arow + k0 + 16);
        float4 b0 = *(const float4*)(Brow + k0);
        float4 b1 = *(const float4*)(Brow + k0 + 16);
        __syncthreads();   // previous iteration's LDS reads done
        As[lc + 0][lr] = a0.x; As[lc + 1][lr] = a0.y;
        As[lc + 2][lr] = a0.z; As[lc + 3][lr] = a0.w;
        As[lc + 16][lr] = a1.x; As[lc + 17][lr] = a1.y;
        As[lc + 18][lr] = a1.z; As[lc + 19][lr] = a1.w;
        Bs[lc + 0][lr] = b0.x; Bs[lc + 1][lr] = b0.y;
        Bs[lc + 2][lr] = b0.z; Bs[lc + 3][lr] = b0.w;
        Bs[lc + 16][lr] = b1.x; Bs[lc + 17][lr] = b1.y;
        Bs[lc + 18][lr] = b1.z; Bs[lc + 19][lr] = b1.w;
        __syncthreads();

        float inner[4][4];
#pragma unroll
        for (int i = 0; i < 4; i++)
#pragma unroll
            for (int j = 0; j < 4; j++) inner[i][j] = 0.0f;

#pragma unroll
        for (int k = 0; k < 32; k++) {
            float4 av = *(const float4*)(&As[k][ty << 2]);
            float4 bv = *(const float4*)(&Bs[k][tx << 2]);
            float aa[4] = {av.x, av.y, av.z, av.w};
            float bb[4] = {bv.x, bv.y, bv.z, bv.w};
#pragma unroll
            for (int i = 0; i < 4; i++)
#pragma unroll
                for (int j = 0; j < 4; j++)
                    inner[i][j] = fmaf(aa[i], bb[j], inner[i][j]);
        }
#pragma unroll
        for (int i = 0; i < 4; i++)
#pragma unroll
            for (int j = 0; j < 4; j++) acc[i][j] += (double)inner[i][j];
    }

#pragma unroll
    for (int i = 0; i < 4; i++) {
        const int m = bm + (ty << 2) + i;
#pragma unroll
        for (int j = 0; j < 4; j++) {
            const int n = bn + (tx << 2) + j;
            unsafeAtomicAdd(&logits[(size_t)m * NEXP + n], (float)acc[i][j]);
        }
    }
}

// ---------------------------------------------------------------------------
// Kernel 2: one wave per token. lane l holds experts 4l..4l+3.
// Replicates jax.lax.top_k semantics exactly: descending, ties -> lower index;
// unselected groups contribute literal 0.0f candidates.
// ---------------------------------------------------------------------------
__global__ __launch_bounds__(256)
void router_topk_kernel(const float* __restrict__ logits,
                        const float* __restrict__ bias,
                        const float* __restrict__ corr,
                        float* __restrict__ out)
{
    const int lane = threadIdx.x & 63;
    const int wave = threadIdx.x >> 6;
    const int t = blockIdx.x * 4 + wave;
    const float* row = logits + (size_t)t * NEXP;
    const int e0 = lane << 2;

    float4 lg = *(const float4*)(row + e0);
    float4 bb = *(const float4*)(bias + e0);
    float4 cc = *(const float4*)(corr + e0);

    float xs[4] = {lg.x + bb.x, lg.y + bb.y, lg.z + bb.z, lg.w + bb.w};
    float cs[4] = {cc.x, cc.y, cc.z, cc.w};
    float s[4], sc[4], mv[4];
#pragma unroll
    for (int i = 0; i < 4; i++) {
        s[i] = 1.0f / (1.0f + expf(-xs[i]));
        sc[i] = s[i] + cs[i];
    }

    // ---- per-group (32 experts = 8 lanes) top-2 sum ----
    float m1 = fmaxf(sc[0], sc[1]);
    float m2 = fminf(sc[0], sc[1]);
    if (sc[2] > m1) { m2 = m1; m1 = sc[2]; } else { m2 = fmaxf(m2, sc[2]); }
    if (sc[3] > m1) { m2 = m1; m1 = sc[3]; } else { m2 = fmaxf(m2, sc[3]); }
#pragma unroll
    for (int off = 1; off <= 4; off <<= 1) {
        float o1 = __shfl_xor(m1, off);
        float o2 = __shfl_xor(m2, off);
        float hi = fmaxf(m1, o1);
        float lo = fminf(m1, o1);
        m1 = hi;
        m2 = fmaxf(lo, fmaxf(m2, o2));
    }
    const float gscore = m1 + m2;

    // ---- broadcast all 8 group scores, compute top-4 group mask ----
    float gs[8];
#pragma unroll
    for (int j = 0; j < 8; j++) gs[j] = __shfl(gscore, j << 3);
    const int g = lane >> 3;
    int rank = 0;
#pragma unroll
    for (int j = 0; j < 8; j++)
        rank += ((gs[j] > gs[g]) || ((gs[j] == gs[g]) && (j < g))) ? 1 : 0;
    const bool sel = (rank < 4);

#pragma unroll
    for (int i = 0; i < 4; i++) mv[i] = sel ? sc[i] : 0.0f;

    // ---- iterative top-8 wave argmax (stable: ties -> lower index) ----
    int oidx[8];
    float ow[8];
    float wsum = 0.0f;
#pragma unroll
    for (int r = 0; r < 8; r++) {
        float bv = mv[0]; int bi = e0;
        if (mv[1] > bv) { bv = mv[1]; bi = e0 + 1; }
        if (mv[2] > bv) { bv = mv[2]; bi = e0 + 2; }
        if (mv[3] > bv) { bv = mv[3]; bi = e0 + 3; }
#pragma unroll
        for (int off = 32; off >= 1; off >>= 1) {
            float ov = __shfl_xor(bv, off);
            int oi = __shfl_xor(bi, off);
            if ((ov > bv) || ((ov == bv) && (oi < bi))) { bv = ov; bi = oi; }
        }
        // all lanes now agree on (bv, bi)
        const int wl = bi >> 2;
        const int slot = bi & 3;
        float sraw = (slot == 0) ? s[0] : (slot == 1) ? s[1] : (slot == 2) ? s[2] : s[3];
        sraw = __shfl(sraw, wl);
        if (lane == wl) {
            if (slot == 0) mv[0] = -1e30f;
            else if (slot == 1) mv[1] = -1e30f;
            else if (slot == 2) mv[2] = -1e30f;
            else mv[3] = -1e30f;
        }
        oidx[r] = bi;
        ow[r] = sraw;
        wsum += sraw;
    }

    if (lane == 0) {
        const float d = wsum + 1e-20f;
        float* oi_p = out + (size_t)t * 8;
        float* ow_p = out + (size_t)NTOK * 8 + (size_t)t * 8;
#pragma unroll
        for (int r = 0; r < 8; r++) {
            oi_p[r] = (float)oidx[r];
            ow_p[r] = (ow[r] / d) * 2.5f;
        }
    }
}

extern "C" void kernel_launch(void* const* d_in, const int* in_sizes, int n_in,
                              void* d_out, int out_size, void* d_ws, size_t ws_size,
                              hipStream_t stream)
{
    const float* hs   = (const float*)d_in[0];   // [8192, 7168]
    const float* W    = (const float*)d_in[1];   // [256, 7168]
    const float* b    = (const float*)d_in[2];   // [256]
    const float* corr = (const float*)d_in[3];   // [256]
    float* out = (float*)d_out;                  // 65536 idx-as-float + 65536 weights
    float* logits = (float*)d_ws;                // 8192*256 fp32 = 8 MB scratch

    // zero the logits accumulator (split-K atomics land here)
    hipMemsetAsync(logits, 0, (size_t)NTOK * NEXP * sizeof(float), stream);

    dim3 g1(NEXP / 64, NTOK / 64, KSPLIT);       // (4, 128, 4) -> 2048 blocks
    router_gemm_kernel<<<g1, 256, 0, stream>>>(hs, W, logits);
    router_topk_kernel<<<NTOK / 4, 256, 0, stream>>>(logits, b, corr, out);
}

// Round 3
// 710.981 us; speedup vs baseline: 1.1609x; 1.0243x over previous
//
#include <hip/hip_runtime.h>
#include <math.h>

#define HDIM 7168
#define NEXP 256
#define NTOK 8192
#define BM 128
#define BN 64
#define BK 32
#define KSPLIT 8
#define KCHUNK (HDIM / KSPLIT)   // 896 -> 28 iterations of BK=32

// ---------------------------------------------------------------------------
// Kernel 1: router GEMM  logits[t][e] = sum_k hs[t][k] * W[e][k]
// BM=128, BN=64, BK=32, 256 threads, 8x4 micro-tile, split-K=8.
// All-fp32 hierarchical accumulation: inner fp32 over each 32-k chunk,
// fp32 chunk accumulator (28 adds), fp32 atomic combine across 8 K-chunks.
// Total logit error ~2e-7 (vs top-k decision gaps ~1e-2).
// LDS: A pad 132, B pad 68 -> staging writes 2-way (free), inner reads
// broadcast/2-way (free).
// ---------------------------------------------------------------------------
__global__ __launch_bounds__(256, 4)
void router_gemm_kernel(const float* __restrict__ hs,
                        const float* __restrict__ W,
                        float* __restrict__ logits)
{
    __shared__ float As[BK][132];   // [k][m], 132%32=4 -> write banks spread
    __shared__ float Bs[BK][68];    // [k][n]

    const int tid = threadIdx.x;
    const int bm = blockIdx.y * BM;
    const int bn = blockIdx.x * BN;
    const int kbase = blockIdx.z * KCHUNK;
    const int tx = tid & 15;        // n micro index (4 cols)
    const int ty = tid >> 4;        // m micro index (8 rows)

    // A staging: thread loads 16 contiguous floats of one row
    const int lrA = tid >> 1;           // row 0..127
    const int lcA = (tid & 1) << 4;     // k-offset 0 or 16
    // B staging: thread loads 2 float4s (k at lcB and lcB+16) of one row
    const int lrB = tid >> 2;           // row 0..63
    const int lcB = (tid & 3) << 2;     // k-offset 0,4,8,12

    const float* Arow = hs + (size_t)(bm + lrA) * HDIM + kbase + lcA;
    const float* Brow = W  + (size_t)(bn + lrB) * HDIM + kbase + lcB;

    float acc[8][4];
#pragma unroll
    for (int i = 0; i < 8; i++)
#pragma unroll
        for (int j = 0; j < 4; j++) acc[i][j] = 0.0f;

    for (int k0 = 0; k0 < KCHUNK; k0 += BK) {
        float4 a0 = *(const float4*)(Arow + k0);
        float4 a1 = *(const float4*)(Arow + k0 + 4);
        float4 a2 = *(const float4*)(Arow + k0 + 8);
        float4 a3 = *(const float4*)(Arow + k0 + 12);
        float4 b0 = *(const float4*)(Brow + k0);
        float4 b1 = *(const float4*)(Brow + k0 + 16);
        __syncthreads();   // previous iteration's LDS reads done
        As[lcA +  0][lrA] = a0.x; As[lcA +  1][lrA] = a0.y;
        As[lcA +  2][lrA] = a0.z; As[lcA +  3][lrA] = a0.w;
        As[lcA +  4][lrA] = a1.x; As[lcA +  5][lrA] = a1.y;
        As[lcA +  6][lrA] = a1.z; As[lcA +  7][lrA] = a1.w;
        As[lcA +  8][lrA] = a2.x; As[lcA +  9][lrA] = a2.y;
        As[lcA + 10][lrA] = a2.z; As[lcA + 11][lrA] = a2.w;
        As[lcA + 12][lrA] = a3.x; As[lcA + 13][lrA] = a3.y;
        As[lcA + 14][lrA] = a3.z; As[lcA + 15][lrA] = a3.w;
        Bs[lcB +  0][lrB] = b0.x; Bs[lcB +  1][lrB] = b0.y;
        Bs[lcB +  2][lrB] = b0.z; Bs[lcB +  3][lrB] = b0.w;
        Bs[lcB + 16][lrB] = b1.x; Bs[lcB + 17][lrB] = b1.y;
        Bs[lcB + 18][lrB] = b1.z; Bs[lcB + 19][lrB] = b1.w;
        __syncthreads();

        float inner[8][4];
#pragma unroll
        for (int i = 0; i < 8; i++)
#pragma unroll
            for (int j = 0; j < 4; j++) inner[i][j] = 0.0f;

#pragma unroll
        for (int k = 0; k < BK; k++) {
            float4 av0 = *(const float4*)(&As[k][ty << 3]);
            float4 av1 = *(const float4*)(&As[k][(ty << 3) + 4]);
            float4 bv  = *(const float4*)(&Bs[k][tx << 2]);
            float aa[8] = {av0.x, av0.y, av0.z, av0.w, av1.x, av1.y, av1.z, av1.w};
            float bb[4] = {bv.x, bv.y, bv.z, bv.w};
#pragma unroll
            for (int i = 0; i < 8; i++)
#pragma unroll
                for (int j = 0; j < 4; j++)
                    inner[i][j] = fmaf(aa[i], bb[j], inner[i][j]);
        }
#pragma unroll
        for (int i = 0; i < 8; i++)
#pragma unroll
            for (int j = 0; j < 4; j++) acc[i][j] += inner[i][j];
    }

#pragma unroll
    for (int i = 0; i < 8; i++) {
        const int m = bm + (ty << 3) + i;
#pragma unroll
        for (int j = 0; j < 4; j++) {
            const int n = bn + (tx << 2) + j;
            unsafeAtomicAdd(&logits[(size_t)m * NEXP + n], acc[i][j]);
        }
    }
}

// ---------------------------------------------------------------------------
// Kernel 2: one wave per token. lane l holds experts 4l..4l+3.
// Replicates jax.lax.top_k semantics exactly: descending, ties -> lower index;
// unselected groups contribute literal 0.0f candidates.
// ---------------------------------------------------------------------------
__global__ __launch_bounds__(256)
void router_topk_kernel(const float* __restrict__ logits,
                        const float* __restrict__ bias,
                        const float* __restrict__ corr,
                        float* __restrict__ out)
{
    const int lane = threadIdx.x & 63;
    const int wave = threadIdx.x >> 6;
    const int t = blockIdx.x * 4 + wave;
    const float* row = logits + (size_t)t * NEXP;
    const int e0 = lane << 2;

    float4 lg = *(const float4*)(row + e0);
    float4 bb = *(const float4*)(bias + e0);
    float4 cc = *(const float4*)(corr + e0);

    float xs[4] = {lg.x + bb.x, lg.y + bb.y, lg.z + bb.z, lg.w + bb.w};
    float cs[4] = {cc.x, cc.y, cc.z, cc.w};
    float s[4], sc[4], mv[4];
#pragma unroll
    for (int i = 0; i < 4; i++) {
        s[i] = 1.0f / (1.0f + expf(-xs[i]));
        sc[i] = s[i] + cs[i];
    }

    // ---- per-group (32 experts = 8 lanes) top-2 sum ----
    float m1 = fmaxf(sc[0], sc[1]);
    float m2 = fminf(sc[0], sc[1]);
    if (sc[2] > m1) { m2 = m1; m1 = sc[2]; } else { m2 = fmaxf(m2, sc[2]); }
    if (sc[3] > m1) { m2 = m1; m1 = sc[3]; } else { m2 = fmaxf(m2, sc[3]); }
#pragma unroll
    for (int off = 1; off <= 4; off <<= 1) {
        float o1 = __shfl_xor(m1, off);
        float o2 = __shfl_xor(m2, off);
        float hi = fmaxf(m1, o1);
        float lo = fminf(m1, o1);
        m1 = hi;
        m2 = fmaxf(lo, fmaxf(m2, o2));
    }
    const float gscore = m1 + m2;

    // ---- broadcast all 8 group scores, compute top-4 group mask ----
    float gs[8];
#pragma unroll
    for (int j = 0; j < 8; j++) gs[j] = __shfl(gscore, j << 3);
    const int g = lane >> 3;
    int rank = 0;
#pragma unroll
    for (int j = 0; j < 8; j++)
        rank += ((gs[j] > gs[g]) || ((gs[j] == gs[g]) && (j < g))) ? 1 : 0;
    const bool sel = (rank < 4);

#pragma unroll
    for (int i = 0; i < 4; i++) mv[i] = sel ? sc[i] : 0.0f;

    // ---- iterative top-8 wave argmax (stable: ties -> lower index) ----
    int oidx[8];
    float ow[8];
    float wsum = 0.0f;
#pragma unroll
    for (int r = 0; r < 8; r++) {
        float bv = mv[0]; int bi = e0;
        if (mv[1] > bv) { bv = mv[1]; bi = e0 + 1; }
        if (mv[2] > bv) { bv = mv[2]; bi = e0 + 2; }
        if (mv[3] > bv) { bv = mv[3]; bi = e0 + 3; }
#pragma unroll
        for (int off = 32; off >= 1; off >>= 1) {
            float ov = __shfl_xor(bv, off);
            int oi = __shfl_xor(bi, off);
            if ((ov > bv) || ((ov == bv) && (oi < bi))) { bv = ov; bi = oi; }
        }
        // all lanes now agree on (bv, bi)
        const int wl = bi >> 2;
        const int slot = bi & 3;
        float sraw = (slot == 0) ? s[0] : (slot == 1) ? s[1] : (slot == 2) ? s[2] : s[3];
        sraw = __shfl(sraw, wl);
        if (lane == wl) {
            if (slot == 0) mv[0] = -1e30f;
            else if (slot == 1) mv[1] = -1e30f;
            else if (slot == 2) mv[2] = -1e30f;
            else mv[3] = -1e30f;
        }
        oidx[r] = bi;
        ow[r] = sraw;
        wsum += sraw;
    }

    if (lane == 0) {
        const float d = wsum + 1e-20f;
        float* oi_p = out + (size_t)t * 8;
        float* ow_p = out + (size_t)NTOK * 8 + (size_t)t * 8;
#pragma unroll
        for (int r = 0; r < 8; r++) {
            oi_p[r] = (float)oidx[r];
            ow_p[r] = (ow[r] / d) * 2.5f;
        }
    }
}

extern "C" void kernel_launch(void* const* d_in, const int* in_sizes, int n_in,
                              void* d_out, int out_size, void* d_ws, size_t ws_size,
                              hipStream_t stream)
{
    const float* hs   = (const float*)d_in[0];   // [8192, 7168]
    const float* W    = (const float*)d_in[1];   // [256, 7168]
    const float* b    = (const float*)d_in[2];   // [256]
    const float* corr = (const float*)d_in[3];   // [256]
    float* out = (float*)d_out;                  // 65536 idx-as-float + 65536 weights
    float* logits = (float*)d_ws;                // 8192*256 fp32 = 8 MB scratch

    // zero the logits accumulator (split-K atomics land here)
    hipMemsetAsync(logits, 0, (size_t)NTOK * NEXP * sizeof(float), stream);

    dim3 g1(NEXP / BN, NTOK / BM, KSPLIT);       // (4, 64, 8) -> 2048 blocks
    router_gemm_kernel<<<g1, 256, 0, stream>>>(hs, W, logits);
    router_topk_kernel<<<NTOK / 4, 256, 0, stream>>>(logits, b, corr, out);
}

// Round 4
// 434.245 us; speedup vs baseline: 1.9007x; 1.6373x over previous
//
#include <hip/hip_runtime.h>
#include <math.h>

#define HDIM 7168
#define NEXP 256
#define NTOK 8192
#define BM 128
#define BN 64
#define KS 4
#define KCH (HDIM / KS)      // 1792 source-k per block
#define NR (KCH / 32)        // 56 staging rounds of 32 source-k
#define PITCH 72             // f16 slots per LDS row: 32 hi | 32 lo | 8 pad

typedef _Float16 f16x8 __attribute__((ext_vector_type(8)));
typedef float f32x4 __attribute__((ext_vector_type(4)));

__device__ __forceinline__ f16x8 hi8(float4 u, float4 v) {
    f16x8 h;
    h[0] = (_Float16)u.x; h[1] = (_Float16)u.y; h[2] = (_Float16)u.z; h[3] = (_Float16)u.w;
    h[4] = (_Float16)v.x; h[5] = (_Float16)v.y; h[6] = (_Float16)v.z; h[7] = (_Float16)v.w;
    return h;
}
__device__ __forceinline__ f16x8 lo8(float4 u, float4 v, f16x8 h) {
    f16x8 l;
    l[0] = (_Float16)(u.x - (float)h[0]); l[1] = (_Float16)(u.y - (float)h[1]);
    l[2] = (_Float16)(u.z - (float)h[2]); l[3] = (_Float16)(u.w - (float)h[3]);
    l[4] = (_Float16)(v.x - (float)h[4]); l[5] = (_Float16)(v.y - (float)h[5]);
    l[6] = (_Float16)(v.z - (float)h[6]); l[7] = (_Float16)(v.w - (float)h[7]);
    return l;
}

// ---------------------------------------------------------------------------
// Router GEMM via f16 MFMA 2-term split: logits = hs @ W^T.
// a = ah + al (f16 each); C = Ah*Bh + Ah*Bl + Al*Bh  (al*bl ~ 2^-20, dropped).
// W pre-scaled x256 so W_lo is f16-normal; epilogue multiplies by 1/256.
// Verified layouts (learn_hip m89/m91/m120): A/B frag [idx=lane&15][k=quad*8+j],
// C/D col=lane&15, row=quad*4+reg.
// Block 128x64, 4 waves of 64x32 (4x2 tiles of 16x16x32), KSPLIT=4, atomics.
// ---------------------------------------------------------------------------
__global__ __launch_bounds__(256, 3)
void router_gemm_mfma(const float* __restrict__ hs,
                      const float* __restrict__ W,
                      float* __restrict__ logits)
{
    __shared__ __align__(16) _Float16 Alds[BM * PITCH];   // 18432 B
    __shared__ __align__(16) _Float16 Blds[BN * PITCH];   //  9216 B

    const int tid  = threadIdx.x;
    const int lane = tid & 63;
    const int wave = tid >> 6;
    const int bn = blockIdx.x * BN;
    const int bm = blockIdx.y * BM;
    const int kb = blockIdx.z * KCH;

    const int wm = (wave >> 1) * 64;    // wave row band
    const int wn = (wave & 1) * 32;     // wave col band
    const int fm = lane & 15;
    const int quad = lane >> 4;

    // A staging: thread -> row tid>>1 (0..127), k-half (tid&1)*16
    const int arow = tid >> 1;
    const int akh  = (tid & 1) << 4;
    const float* Ap = hs + (size_t)(bm + arow) * HDIM + kb + akh;
    // B staging: thread -> row tid>>2 (0..63), k-quarter (tid&3)*8
    const int brow = tid >> 2;
    const int bkh  = (tid & 3) << 3;
    const float* Bp = W + (size_t)(bn + brow) * HDIM + kb + bkh;

    f32x4 acc[4][2];
#pragma unroll
    for (int i = 0; i < 4; i++)
#pragma unroll
        for (int j = 0; j < 2; j++) acc[i][j] = (f32x4)0.0f;

    // prefetch round 0
    float4 a0 = *(const float4*)(Ap + 0);
    float4 a1 = *(const float4*)(Ap + 4);
    float4 a2 = *(const float4*)(Ap + 8);
    float4 a3 = *(const float4*)(Ap + 12);
    float4 b0 = *(const float4*)(Bp + 0);
    float4 b1 = *(const float4*)(Bp + 4);

    for (int r = 0; r < NR; ++r) {
        __syncthreads();   // previous round's LDS reads complete
        // ---- convert & stage this round ----
        {
            f16x8 h0 = hi8(a0, a1);
            f16x8 h1 = hi8(a2, a3);
            f16x8 l0 = lo8(a0, a1, h0);
            f16x8 l1 = lo8(a2, a3, h1);
            *(f16x8*)&Alds[arow * PITCH + akh]          = h0;
            *(f16x8*)&Alds[arow * PITCH + akh + 8]      = h1;
            *(f16x8*)&Alds[arow * PITCH + 32 + akh]     = l0;
            *(f16x8*)&Alds[arow * PITCH + 32 + akh + 8] = l1;
            float4 s0 = make_float4(b0.x * 256.0f, b0.y * 256.0f, b0.z * 256.0f, b0.w * 256.0f);
            float4 s1 = make_float4(b1.x * 256.0f, b1.y * 256.0f, b1.z * 256.0f, b1.w * 256.0f);
            f16x8 hb = hi8(s0, s1);
            f16x8 lb = lo8(s0, s1, hb);
            *(f16x8*)&Blds[brow * PITCH + bkh]      = hb;
            *(f16x8*)&Blds[brow * PITCH + 32 + bkh] = lb;
        }
        __syncthreads();
        // ---- prefetch next round (latency hidden by MFMA phase) ----
        if (r + 1 < NR) {
            const float* An = Ap + (r + 1) * 32;
            const float* Bn = Bp + (r + 1) * 32;
            a0 = *(const float4*)(An + 0);
            a1 = *(const float4*)(An + 4);
            a2 = *(const float4*)(An + 8);
            a3 = *(const float4*)(An + 12);
            b0 = *(const float4*)(Bn + 0);
            b1 = *(const float4*)(Bn + 4);
        }
        // ---- MFMA: 3 products over this 32-k chunk ----
        f16x8 af[4], bf[2];
#pragma unroll
        for (int im = 0; im < 4; im++)
            af[im] = *(const f16x8*)&Alds[(wm + im * 16 + fm) * PITCH + quad * 8];
#pragma unroll
        for (int in_ = 0; in_ < 2; in_++)
            bf[in_] = *(const f16x8*)&Blds[(wn + in_ * 16 + fm) * PITCH + quad * 8];
        // P1: Ah * Bh
#pragma unroll
        for (int im = 0; im < 4; im++)
#pragma unroll
            for (int in_ = 0; in_ < 2; in_++)
                acc[im][in_] = __builtin_amdgcn_mfma_f32_16x16x32_f16(af[im], bf[in_], acc[im][in_], 0, 0, 0);
        // P2: Ah * Bl
        {
            f16x8 bl[2];
#pragma unroll
            for (int in_ = 0; in_ < 2; in_++)
                bl[in_] = *(const f16x8*)&Blds[(wn + in_ * 16 + fm) * PITCH + 32 + quad * 8];
#pragma unroll
            for (int im = 0; im < 4; im++)
#pragma unroll
                for (int in_ = 0; in_ < 2; in_++)
                    acc[im][in_] = __builtin_amdgcn_mfma_f32_16x16x32_f16(af[im], bl[in_], acc[im][in_], 0, 0, 0);
        }
        // P3: Al * Bh
        {
            f16x8 al[4];
#pragma unroll
            for (int im = 0; im < 4; im++)
                al[im] = *(const f16x8*)&Alds[(wm + im * 16 + fm) * PITCH + 32 + quad * 8];
#pragma unroll
            for (int im = 0; im < 4; im++)
#pragma unroll
                for (int in_ = 0; in_ < 2; in_++)
                    acc[im][in_] = __builtin_amdgcn_mfma_f32_16x16x32_f16(al[im], bf[in_], acc[im][in_], 0, 0, 0);
        }
    }

    // ---- epilogue: undo x256 on B, combine K-splits via atomics ----
#pragma unroll
    for (int im = 0; im < 4; im++) {
#pragma unroll
        for (int in_ = 0; in_ < 2; in_++) {
            const int n = bn + wn + in_ * 16 + fm;
#pragma unroll
            for (int rr = 0; rr < 4; rr++) {
                const int m = bm + wm + im * 16 + quad * 4 + rr;
                unsafeAtomicAdd(&logits[(size_t)m * NEXP + n], acc[im][in_][rr] * 0.00390625f);
            }
        }
    }
}

// ---------------------------------------------------------------------------
// Kernel 2: one wave per token. lane l holds experts 4l..4l+3.
// Replicates jax.lax.top_k semantics exactly: descending, ties -> lower index;
// unselected groups contribute literal 0.0f candidates.
// ---------------------------------------------------------------------------
__global__ __launch_bounds__(256)
void router_topk_kernel(const float* __restrict__ logits,
                        const float* __restrict__ bias,
                        const float* __restrict__ corr,
                        float* __restrict__ out)
{
    const int lane = threadIdx.x & 63;
    const int wave = threadIdx.x >> 6;
    const int t = blockIdx.x * 4 + wave;
    const float* row = logits + (size_t)t * NEXP;
    const int e0 = lane << 2;

    float4 lg = *(const float4*)(row + e0);
    float4 bb = *(const float4*)(bias + e0);
    float4 cc = *(const float4*)(corr + e0);

    float xs[4] = {lg.x + bb.x, lg.y + bb.y, lg.z + bb.z, lg.w + bb.w};
    float cs[4] = {cc.x, cc.y, cc.z, cc.w};
    float s[4], sc[4], mv[4];
#pragma unroll
    for (int i = 0; i < 4; i++) {
        s[i] = 1.0f / (1.0f + expf(-xs[i]));
        sc[i] = s[i] + cs[i];
    }

    // ---- per-group (32 experts = 8 lanes) top-2 sum ----
    float m1 = fmaxf(sc[0], sc[1]);
    float m2 = fminf(sc[0], sc[1]);
    if (sc[2] > m1) { m2 = m1; m1 = sc[2]; } else { m2 = fmaxf(m2, sc[2]); }
    if (sc[3] > m1) { m2 = m1; m1 = sc[3]; } else { m2 = fmaxf(m2, sc[3]); }
#pragma unroll
    for (int off = 1; off <= 4; off <<= 1) {
        float o1 = __shfl_xor(m1, off);
        float o2 = __shfl_xor(m2, off);
        float hi = fmaxf(m1, o1);
        float lo = fminf(m1, o1);
        m1 = hi;
        m2 = fmaxf(lo, fmaxf(m2, o2));
    }
    const float gscore = m1 + m2;

    // ---- broadcast all 8 group scores, compute top-4 group mask ----
    float gs[8];
#pragma unroll
    for (int j = 0; j < 8; j++) gs[j] = __shfl(gscore, j << 3);
    const int g = lane >> 3;
    int rank = 0;
#pragma unroll
    for (int j = 0; j < 8; j++)
        rank += ((gs[j] > gs[g]) || ((gs[j] == gs[g]) && (j < g))) ? 1 : 0;
    const bool sel = (rank < 4);

#pragma unroll
    for (int i = 0; i < 4; i++) mv[i] = sel ? sc[i] : 0.0f;

    // ---- iterative top-8 wave argmax (stable: ties -> lower index) ----
    int oidx[8];
    float ow[8];
    float wsum = 0.0f;
#pragma unroll
    for (int r = 0; r < 8; r++) {
        float bv = mv[0]; int bi = e0;
        if (mv[1] > bv) { bv = mv[1]; bi = e0 + 1; }
        if (mv[2] > bv) { bv = mv[2]; bi = e0 + 2; }
        if (mv[3] > bv) { bv = mv[3]; bi = e0 + 3; }
#pragma unroll
        for (int off = 32; off >= 1; off >>= 1) {
            float ov = __shfl_xor(bv, off);
            int oi = __shfl_xor(bi, off);
            if ((ov > bv) || ((ov == bv) && (oi < bi))) { bv = ov; bi = oi; }
        }
        // all lanes now agree on (bv, bi)
        const int wl = bi >> 2;
        const int slot = bi & 3;
        float sraw = (slot == 0) ? s[0] : (slot == 1) ? s[1] : (slot == 2) ? s[2] : s[3];
        sraw = __shfl(sraw, wl);
        if (lane == wl) {
            if (slot == 0) mv[0] = -1e30f;
            else if (slot == 1) mv[1] = -1e30f;
            else if (slot == 2) mv[2] = -1e30f;
            else mv[3] = -1e30f;
        }
        oidx[r] = bi;
        ow[r] = sraw;
        wsum += sraw;
    }

    if (lane == 0) {
        const float d = wsum + 1e-20f;
        float* oi_p = out + (size_t)t * 8;
        float* ow_p = out + (size_t)NTOK * 8 + (size_t)t * 8;
#pragma unroll
        for (int r = 0; r < 8; r++) {
            oi_p[r] = (float)oidx[r];
            ow_p[r] = (ow[r] / d) * 2.5f;
        }
    }
}

extern "C" void kernel_launch(void* const* d_in, const int* in_sizes, int n_in,
                              void* d_out, int out_size, void* d_ws, size_t ws_size,
                              hipStream_t stream)
{
    const float* hs   = (const float*)d_in[0];   // [8192, 7168]
    const float* W    = (const float*)d_in[1];   // [256, 7168]
    const float* b    = (const float*)d_in[2];   // [256]
    const float* corr = (const float*)d_in[3];   // [256]
    float* out = (float*)d_out;                  // 65536 idx-as-float + 65536 weights
    float* logits = (float*)d_ws;                // 8192*256 fp32 = 8 MB scratch

    // zero the logits accumulator (split-K atomics land here)
    hipMemsetAsync(logits, 0, (size_t)NTOK * NEXP * sizeof(float), stream);

    dim3 g1(NEXP / BN, NTOK / BM, KS);           // (4, 64, 4) -> 1024 blocks
    router_gemm_mfma<<<g1, 256, 0, stream>>>(hs, W, logits);
    router_topk_kernel<<<NTOK / 4, 256, 0, stream>>>(logits, b, corr, out);
}